// Round 2
// baseline (3817.995 us; speedup 1.0000x reference)
//
#include <hip/hip_runtime.h>
#include <hip/hip_cooperative_groups.h>

namespace cg = cooperative_groups;

typedef unsigned int uint;
typedef unsigned short ushort;
typedef __attribute__((ext_vector_type(4))) float f4;
typedef __attribute__((ext_vector_type(8))) short bf8;

#define T_ 256
#define B_ 64
#define E_ 256
#define HD_ 256
#define NTAG 20

// ---- workspace layout (float offsets) ----
#define GX_OFF 0ull           // gx planes [2*16][256 t][64 b][64 g]  (33,554,432 f)
#define LG_OFF 33554432ull    // logits [256*64][20] (327,680 f)
#define Q_OFFF 33882112ull    // ushort area starts here

// ---- q (ushort) offsets ----
#define WHHF_HI 0u
#define WHHB_HI 524288u
#define WIHF_HI 1048576u
#define WIHB_HI 1572864u
#define LO_D    262144u       // lo = hi + LO_D for the 4 weight matrices
#define WL_HI   2097152u
#define WL_LO   2107392u
#define HS_HI   2117632u      // h hi-planes [2 dir][257 slot][64 row][256 u]
#define HS_LO   10539008u     // h lo-planes same shape
#define HS_DIR  4210688ull    // per-dir stride (257*16384)

__device__ __forceinline__ ushort f2bf(float x){
  uint u = __float_as_uint(x);
  uint r = (u + 0x7fffu + ((u >> 16) & 1u)) >> 16;
  return (ushort)r;
}
__device__ __forceinline__ float bf2f(ushort h){ return __uint_as_float(((uint)h) << 16); }
__device__ __forceinline__ void splitf(float x, ushort &h, ushort &l){
  h = f2bf(x);
  l = f2bf(x - bf2f(h));
}
__device__ __forceinline__ f4 mfma16(bf8 a, bf8 b, f4 c){
  return __builtin_amdgcn_mfma_f32_16x16x32_bf16(a, b, c, 0, 0, 0);
}
__device__ __forceinline__ float sigm(float x){ return 1.0f / (1.0f + expf(-x)); }

// ============ K0: split weights + h0 into bf16 hi/lo ============
__global__ void k0_split(const float* __restrict__ whhF, const float* __restrict__ whhB,
                         const float* __restrict__ wihF, const float* __restrict__ wihB,
                         const float* __restrict__ wl, const float* __restrict__ h0,
                         ushort* __restrict__ q){
  uint stride = gridDim.x * blockDim.x;
  for (uint i = blockIdx.x * blockDim.x + threadIdx.x; i < 1091584u; i += stride){
    float x; uint hbase;
    if (i < 262144u){ x = whhF[i]; hbase = WHHF_HI + i; }
    else if (i < 524288u){ x = whhB[i - 262144u]; hbase = WHHB_HI + (i - 262144u); }
    else if (i < 786432u){ x = wihF[i - 524288u]; hbase = WIHF_HI + (i - 524288u); }
    else if (i < 1048576u){ x = wihB[i - 786432u]; hbase = WIHB_HI + (i - 786432u); }
    else if (i < 1058816u){
      uint j = i - 1048576u; // < 10240
      ushort h, l; splitf(wl[j], h, l);
      q[WL_HI + j] = h; q[WL_LO + j] = l;
      continue;
    } else {
      uint j = i - 1058816u; // < 32768: h0[2][64][256] -> slot 0 per dir
      uint dir = j >> 14, rem = j & 16383u;
      ushort h, l; splitf(h0[j], h, l);
      q[HS_HI + dir * (uint)HS_DIR + rem] = h;
      q[HS_LO + dir * (uint)HS_DIR + rem] = l;
      continue;
    }
    ushort h, l; splitf(x, h, l);
    q[hbase] = h; q[hbase + LO_D] = l;
  }
}

// ============ K1: gx = x @ WihT + bih + bhh, written to per-(dir,ugrp) planes ============
__global__ __launch_bounds__(256) void k1_gx(const int* __restrict__ sents,
    const float* __restrict__ emb, const ushort* __restrict__ q,
    const float* __restrict__ bihF, const float* __restrict__ bhhF,
    const float* __restrict__ bihB, const float* __restrict__ bhhB,
    float* __restrict__ gx)
{
  __shared__ ushort Bs[2][64][256]; // 64 KiB, XOR-swizzled 16B chunks
  const int tid = threadIdx.x;
  const int dir = blockIdx.z;
  const int n0 = blockIdx.x * 64;
  const int r0 = blockIdx.y * 64;
  const ushort* whi = q + (dir ? WIHB_HI : WIHF_HI);

  for (int cid = tid; cid < 4096; cid += 256){
    int half = cid >> 11;
    int c = (cid >> 5) & 63;
    int kc = cid & 31;
    const ushort* src = whi + half * LO_D + (size_t)(n0 + c) * 256 + kc * 8;
    uint4 v = *(const uint4*)src;
    *(uint4*)&Bs[half][c][(kc ^ (c & 31)) * 8] = v;
  }
  __syncthreads();

  const int w = tid >> 6, l = tid & 63;
  const int lrow = l & 15, lk8 = (l >> 4) * 8;
  const int r = r0 + w * 16 + lrow;
  const int t = r >> 6, b = r & 63;
  const int tok = sents[b * T_ + (dir ? (T_ - 1 - t) : t)];
  const float* arow = emb + (size_t)tok * E_;

  f4 acc[4];
  #pragma unroll
  for (int i = 0; i < 4; i++){ acc[i][0]=0.f; acc[i][1]=0.f; acc[i][2]=0.f; acc[i][3]=0.f; }

  for (int ks = 0; ks < 8; ks++){
    const float* ap = arow + ks * 32 + lk8;
    f4 v0 = *(const f4*)ap;
    f4 v1 = *(const f4*)(ap + 4);
    bf8 ah, al;
    #pragma unroll
    for (int j = 0; j < 4; j++){
      ushort hh, ll;
      splitf(v0[j], hh, ll); ah[j] = (short)hh; al[j] = (short)ll;
      splitf(v1[j], hh, ll); ah[4 + j] = (short)hh; al[4 + j] = (short)ll;
    }
    const int kc = ks * 4 + (l >> 4);
    #pragma unroll
    for (int nt = 0; nt < 4; nt++){
      const int c = nt * 16 + lrow;
      const int skc = kc ^ (c & 31);
      bf8 bh = *(const bf8*)&Bs[0][c][skc * 8];
      bf8 blo = *(const bf8*)&Bs[1][c][skc * 8];
      acc[nt] = mfma16(ah, bh, acc[nt]);
      acc[nt] = mfma16(ah, blo, acc[nt]);
      acc[nt] = mfma16(al, bh, acc[nt]);
    }
  }

  const float* bih = dir ? bihB : bihF;
  const float* bhh = dir ? bhhB : bhhF;
  #pragma unroll
  for (int nt = 0; nt < 4; nt++){
    int col = n0 + nt * 16 + lrow;       // gate-major column in [0,1024)
    float bias = bih[col] + bhh[col];
    int gate = col >> 8, un = col & 255;
    size_t plane = (size_t)(dir * 16 + (un >> 4));
    int u15 = un & 15;
    #pragma unroll
    for (int reg = 0; reg < 4; reg++){
      int row = r0 + w * 16 + (l >> 4) * 4 + reg;
      int tt = row >> 6, bb = row & 63;
      gx[((plane * 256 + tt) * 64 + bb) * 64 + gate * 16 + u15] = acc[nt][reg] + bias;
    }
  }
}

// ============ K2: persistent recurrence, weights LDS-resident, c in regs ============
__global__ __launch_bounds__(256) void k2_persist(const ushort* __restrict__ q,
    const float* __restrict__ gx, const float* __restrict__ c0,
    ushort* __restrict__ hsHi, ushort* __restrict__ hsLo)
{
  cg::grid_group gg = cg::this_grid();
  __shared__ ushort Bs[2][64][256];
  const int tid = threadIdx.x;
  const int bid = blockIdx.x;
  const int dir = bid >> 4;
  const int u0 = (bid & 15) * 16;
  const ushort* whi = q + (dir ? WHHB_HI : WHHF_HI);

  for (int cid = tid; cid < 4096; cid += 256){
    int half = cid >> 11;
    int c = (cid >> 5) & 63;
    int kc = cid & 31;
    int grow = (c >> 4) * 256 + u0 + (c & 15); // gate-strided rows
    const ushort* src = whi + half * LO_D + (size_t)grow * 256 + kc * 8;
    uint4 v = *(const uint4*)src;
    *(uint4*)&Bs[half][c][(kc ^ (c & 31)) * 8] = v;
  }
  __syncthreads();

  const int w = tid >> 6, l = tid & 63;
  const int lrow = l & 15, lk8 = (l >> 4) * 8;
  const int arow = w * 16 + lrow;
  const int unit = u0 + lrow;
  const int erow = w * 16 + (l >> 4) * 4;

  float creg[4];
  #pragma unroll
  for (int reg = 0; reg < 4; reg++)
    creg[reg] = c0[dir * 16384 + (erow + reg) * 256 + unit];

  const float* gxp = gx + (size_t)(dir * 16 + (u0 >> 4)) * (256ull * 4096ull);
  ushort* hHiD = hsHi + (size_t)dir * HS_DIR;
  ushort* hLoD = hsLo + (size_t)dir * HS_DIR;

  for (int t = 0; t < T_; t++){
    // prefetch gate inputs (independent of hprev)
    float gv[4][4];
    #pragma unroll
    for (int reg = 0; reg < 4; reg++)
      #pragma unroll
      for (int gate = 0; gate < 4; gate++)
        gv[reg][gate] = gxp[((size_t)t * 64 + (erow + reg)) * 64 + gate * 16 + lrow];

    const ushort* hHi = hHiD + (size_t)t * 16384;      // slot t = h_{t-1}
    const ushort* hLo = hLoD + (size_t)t * 16384;

    f4 acc[4];
    #pragma unroll
    for (int i = 0; i < 4; i++){ acc[i][0]=0.f; acc[i][1]=0.f; acc[i][2]=0.f; acc[i][3]=0.f; }

    #pragma unroll
    for (int ks = 0; ks < 8; ks++){
      bf8 ah = *(const bf8*)&hHi[arow * 256 + ks * 32 + lk8];
      bf8 al = *(const bf8*)&hLo[arow * 256 + ks * 32 + lk8];
      const int kc = ks * 4 + (l >> 4);
      #pragma unroll
      for (int nt = 0; nt < 4; nt++){
        const int c = nt * 16 + lrow;
        const int skc = kc ^ (c & 31);
        bf8 bh  = *(const bf8*)&Bs[0][c][skc * 8];
        bf8 blo = *(const bf8*)&Bs[1][c][skc * 8];
        acc[nt] = mfma16(ah, bh, acc[nt]);
        acc[nt] = mfma16(ah, blo, acc[nt]);
        acc[nt] = mfma16(al, bh, acc[nt]);
      }
    }

    ushort* oHi = hHiD + (size_t)(t + 1) * 16384;
    ushort* oLo = hLoD + (size_t)(t + 1) * 16384;
    #pragma unroll
    for (int reg = 0; reg < 4; reg++){
      float g0 = acc[0][reg] + gv[reg][0];
      float g1 = acc[1][reg] + gv[reg][1];
      float g2 = acc[2][reg] + gv[reg][2];
      float g3 = acc[3][reg] + gv[reg][3];
      float cn = sigm(g1) * creg[reg] + sigm(g0) * tanhf(g2);
      float hn = sigm(g3) * tanhf(cn);
      creg[reg] = cn;
      ushort hh, ll; splitf(hn, hh, ll);
      oHi[(erow + reg) * 256 + unit] = hh;
      oLo[(erow + reg) * 256 + unit] = ll;
    }

    if (t + 1 < T_){
      __threadfence();   // release: h stores visible device-wide (cross-XCD)
      gg.sync();
      __threadfence();   // acquire: don't read stale h through local caches
    }
  }
}

// ============ K3: logits = [hf|hb] @ WlT + bl (consumes pre-split h) ============
__global__ __launch_bounds__(256) void k3_logits(const ushort* __restrict__ q,
    const float* __restrict__ bl, float* __restrict__ logits)
{
  __shared__ ushort Bs[2][32][512];
  const int tid = threadIdx.x;
  const int r0 = blockIdx.x * 64;
  const ushort* hsHi = q + HS_HI;
  const ushort* hsLo = q + HS_LO;

  for (int cid = tid; cid < 4096; cid += 256){
    int half = cid >> 11;
    int c = (cid >> 6) & 31;
    int kc = cid & 63;
    uint4 v; v.x = 0; v.y = 0; v.z = 0; v.w = 0;
    if (c < NTAG){
      const ushort* src = q + (half ? WL_LO : WL_HI) + (size_t)c * 512 + kc * 8;
      v = *(const uint4*)src;
    }
    *(uint4*)&Bs[half][c][(kc ^ (c & 31)) * 8] = v;
  }
  __syncthreads();

  const int w = tid >> 6, l = tid & 63;
  const int lrow = l & 15, lk8 = (l >> 4) * 8;
  const int r = r0 + w * 16 + lrow;
  const int t = r >> 6, b = r & 63;

  f4 acc[2];
  #pragma unroll
  for (int i = 0; i < 2; i++){ acc[i][0]=0.f; acc[i][1]=0.f; acc[i][2]=0.f; acc[i][3]=0.f; }

  for (int ks = 0; ks < 16; ks++){
    int k = ks * 32 + lk8;
    size_t off;
    if (k < 256)
      off = (size_t)(t + 1) * 16384 + (size_t)b * 256 + k;                    // hf slot t+1
    else
      off = HS_DIR + (size_t)(256 - t) * 16384 + (size_t)b * 256 + (k - 256); // hb slot 256-t
    bf8 ah = *(const bf8*)&hsHi[off];
    bf8 al = *(const bf8*)&hsLo[off];
    int kc = k >> 3;
    #pragma unroll
    for (int nt = 0; nt < 2; nt++){
      int c = nt * 16 + lrow;
      int skc = kc ^ (c & 31);
      bf8 bh  = *(const bf8*)&Bs[0][c][skc * 8];
      bf8 blo = *(const bf8*)&Bs[1][c][skc * 8];
      acc[nt] = mfma16(ah, bh, acc[nt]);
      acc[nt] = mfma16(ah, blo, acc[nt]);
      acc[nt] = mfma16(al, bh, acc[nt]);
    }
  }

  #pragma unroll
  for (int nt = 0; nt < 2; nt++){
    int tag = nt * 16 + lrow;
    if (tag < NTAG){
      float bias = bl[tag];
      #pragma unroll
      for (int reg = 0; reg < 4; reg++){
        int row = r0 + w * 16 + (l >> 4) * 4 + reg;
        logits[(size_t)row * NTAG + tag] = acc[nt][reg] + bias;
      }
    }
  }
}

// ============ K4: Viterbi DP + backtrace + probs + scores ============
__global__ __launch_bounds__(64) void k4_viterbi(const float* __restrict__ logits,
    const float* __restrict__ trans, float* __restrict__ out)
{
  const int b = blockIdx.x, tid = threadIdx.x;
  __shared__ float tr[NTAG][NTAG];
  __shared__ float trell[T_][NTAG];
  __shared__ unsigned char bp[T_][NTAG];
  __shared__ int path[T_];
  __shared__ float cur[NTAG], nv[NTAG];

  for (int i = tid; i < NTAG * NTAG; i += 64) tr[i / NTAG][i % NTAG] = trans[i];
  if (tid < NTAG){
    float v = logits[(size_t)b * NTAG + tid];
    cur[tid] = v; trell[0][tid] = v;
  }
  __syncthreads();

  for (int t = 1; t < T_; t++){
    if (tid < NTAG){
      float best = -3.0e38f; int bi = 0;
      #pragma unroll
      for (int p = 0; p < NTAG; p++){
        float v = cur[p] + tr[p][tid];
        if (v > best){ best = v; bi = p; }   // first-max (strict >)
      }
      float nvv = logits[((size_t)t * 64 + b) * NTAG + tid] + best;
      nv[tid] = nvv; trell[t][tid] = nvv; bp[t][tid] = (unsigned char)bi;
    }
    __syncthreads();
    if (tid < NTAG) cur[tid] = nv[tid];
    __syncthreads();
  }

  if (tid == 0){
    float best = -3.0e38f; int bi = 0;
    for (int c = 0; c < NTAG; c++){
      if (trell[T_ - 1][c] > best){ best = trell[T_ - 1][c]; bi = c; }
    }
    out[b] = best;                 // scores
    path[T_ - 1] = bi;
    for (int t = T_ - 1; t >= 1; t--) path[t - 1] = bp[t][path[t]];
  }
  __syncthreads();

  for (int t = tid; t < T_; t += 64){
    float m = -3.0e38f;
    for (int c = 0; c < NTAG; c++) m = fmaxf(m, trell[t][c]);
    float s = 0.f;
    for (int c = 0; c < NTAG; c++) s += expf(trell[t][c] - m);
    float p = expf(trell[t][path[t]] - m) / s;
    out[64 + (size_t)b * T_ + t] = (float)path[t];          // path.T
    out[64 + 64 * T_ + (size_t)b * T_ + t] = p;             // probs.T
  }
}

extern "C" void kernel_launch(void* const* d_in, const int* in_sizes, int n_in,
                              void* d_out, int out_size, void* d_ws, size_t ws_size,
                              hipStream_t stream){
  (void)in_sizes; (void)n_in; (void)out_size; (void)ws_size;
  const int*   sents = (const int*)d_in[0];
  const float* emb   = (const float*)d_in[1];
  const float* wihF  = (const float*)d_in[2];
  const float* whhF  = (const float*)d_in[3];
  const float* bihF  = (const float*)d_in[4];
  const float* bhhF  = (const float*)d_in[5];
  const float* wihB  = (const float*)d_in[6];
  const float* whhB  = (const float*)d_in[7];
  const float* bihB  = (const float*)d_in[8];
  const float* bhhB  = (const float*)d_in[9];
  const float* wl    = (const float*)d_in[10];
  const float* bl    = (const float*)d_in[11];
  const float* trans = (const float*)d_in[12];
  const float* h0    = (const float*)d_in[13];
  const float* c0    = (const float*)d_in[14];

  float* wsf    = (float*)d_ws;
  ushort* q     = (ushort*)(wsf + Q_OFFF);
  float* gx     = wsf + GX_OFF;
  float* logits = wsf + LG_OFF;
  float* out    = (float*)d_out;
  ushort* hsHi  = q + HS_HI;
  ushort* hsLo  = q + HS_LO;

  k0_split<<<1024, 256, 0, stream>>>(whhF, whhB, wihF, wihB, wl, h0, q);
  k1_gx<<<dim3(16, 256, 2), 256, 0, stream>>>(sents, emb, q, bihF, bhhF, bihB, bhhB, gx);

  {
    const ushort* qa = q; const float* gxa = gx; const float* c0a = c0;
    ushort* hia = hsHi; ushort* loa = hsLo;
    void* args[] = { (void*)&qa, (void*)&gxa, (void*)&c0a, (void*)&hia, (void*)&loa };
    hipLaunchCooperativeKernel((const void*)k2_persist, dim3(32), dim3(256),
                               args, 0, stream);
  }

  k3_logits<<<256, 256, 0, stream>>>(q, bl, logits);
  k4_viterbi<<<64, 64, 0, stream>>>(logits, trans, out);
}

// Round 3
// 1724.096 us; speedup vs baseline: 2.2145x; 2.2145x over previous
//
#include <hip/hip_runtime.h>

typedef unsigned int uint;
typedef unsigned short ushort;
typedef __attribute__((ext_vector_type(4))) float f4;
typedef __attribute__((ext_vector_type(8))) short bf8;

#define T_ 256
#define B_ 64
#define E_ 256
#define HD_ 256
#define NTAG 20

// ---- workspace layout (float offsets) ----
#define GX_OFF 0ull           // gx planes [2*16][256 t][64 b][64 g]  (33,554,432 f)
#define LG_OFF 33554432ull    // logits [256*64][20] (327,680 f)
#define FLG_OFF 33882112ull   // barrier flags: 2 dirs * 1024 uints
#define Q_OFFF 33884160ull    // ushort area starts here

// ---- q (ushort) offsets ----
#define WHHF_HI 0u
#define WHHB_HI 524288u
#define WIHF_HI 1048576u
#define WIHB_HI 1572864u
#define LO_D    262144u       // lo = hi + LO_D for the 4 weight matrices
#define WL_HI   2097152u
#define WL_LO   2107392u
#define HS_HI   2117632u      // h hi-planes [2 dir][257 slot][64 row][256 u]
#define HS_LO   10539008u     // h lo-planes same shape
#define HS_DIR  4210688ull    // per-dir stride (257*16384)

__device__ __forceinline__ ushort f2bf(float x){
  uint u = __float_as_uint(x);
  uint r = (u + 0x7fffu + ((u >> 16) & 1u)) >> 16;
  return (ushort)r;
}
__device__ __forceinline__ float bf2f(ushort h){ return __uint_as_float(((uint)h) << 16); }
__device__ __forceinline__ void splitf(float x, ushort &h, ushort &l){
  h = f2bf(x);
  l = f2bf(x - bf2f(h));
}
__device__ __forceinline__ f4 mfma16(bf8 a, bf8 b, f4 c){
  return __builtin_amdgcn_mfma_f32_16x16x32_bf16(a, b, c, 0, 0, 0);
}
__device__ __forceinline__ float sigm(float x){ return 1.0f / (1.0f + expf(-x)); }

// IC-coherent (cross-XCD) 16B load: bypass L1+L2, read from Infinity Cache.
#define LD16(dst, base, off) \
  asm volatile("global_load_dwordx4 %0, %1, off offset:" #off " sc0 sc1" \
               : "=v"(dst) : "v"(base))
// IC-coherent 2B store: write-through to Infinity Cache.
#define ST2(base, off, val) \
  asm volatile("global_store_short %0, %1, off offset:" #off " sc0 sc1" \
               :: "v"(base), "v"(val) : "memory")

// ============ K0: split weights + h0 into bf16 hi/lo; zero barrier flags ============
__global__ void k0_split(const float* __restrict__ whhF, const float* __restrict__ whhB,
                         const float* __restrict__ wihF, const float* __restrict__ wihB,
                         const float* __restrict__ wl, const float* __restrict__ h0,
                         ushort* __restrict__ q, uint* __restrict__ flags){
  uint stride = gridDim.x * blockDim.x;
  for (uint i = blockIdx.x * blockDim.x + threadIdx.x; i < 1093632u; i += stride){
    float x; uint hbase;
    if (i < 262144u){ x = whhF[i]; hbase = WHHF_HI + i; }
    else if (i < 524288u){ x = whhB[i - 262144u]; hbase = WHHB_HI + (i - 262144u); }
    else if (i < 786432u){ x = wihF[i - 524288u]; hbase = WIHF_HI + (i - 524288u); }
    else if (i < 1048576u){ x = wihB[i - 786432u]; hbase = WIHB_HI + (i - 786432u); }
    else if (i < 1058816u){
      uint j = i - 1048576u; // < 10240
      ushort h, l; splitf(wl[j], h, l);
      q[WL_HI + j] = h; q[WL_LO + j] = l;
      continue;
    } else if (i < 1091584u){
      uint j = i - 1058816u; // < 32768: h0[2][64][256] -> slot 0 per dir
      uint dir = j >> 14, rem = j & 16383u;
      ushort h, l; splitf(h0[j], h, l);
      q[HS_HI + dir * (uint)HS_DIR + rem] = h;
      q[HS_LO + dir * (uint)HS_DIR + rem] = l;
      continue;
    } else {
      __hip_atomic_store(&flags[i - 1091584u], 0u, __ATOMIC_RELAXED,
                         __HIP_MEMORY_SCOPE_AGENT);
      continue;
    }
    ushort h, l; splitf(x, h, l);
    q[hbase] = h; q[hbase + LO_D] = l;
  }
}

// ============ K1: gx = x @ WihT + bih + bhh, written to per-(dir,ugrp) planes ============
__global__ __launch_bounds__(256) void k1_gx(const int* __restrict__ sents,
    const float* __restrict__ emb, const ushort* __restrict__ q,
    const float* __restrict__ bihF, const float* __restrict__ bhhF,
    const float* __restrict__ bihB, const float* __restrict__ bhhB,
    float* __restrict__ gx)
{
  __shared__ ushort Bs[2][64][256]; // 64 KiB, XOR-swizzled 16B chunks
  const int tid = threadIdx.x;
  const int dir = blockIdx.z;
  const int n0 = blockIdx.x * 64;
  const int r0 = blockIdx.y * 64;
  const ushort* whi = q + (dir ? WIHB_HI : WIHF_HI);

  for (int cid = tid; cid < 4096; cid += 256){
    int half = cid >> 11;
    int c = (cid >> 5) & 63;
    int kc = cid & 31;
    const ushort* src = whi + half * LO_D + (size_t)(n0 + c) * 256 + kc * 8;
    uint4 v = *(const uint4*)src;
    *(uint4*)&Bs[half][c][(kc ^ (c & 31)) * 8] = v;
  }
  __syncthreads();

  const int w = tid >> 6, l = tid & 63;
  const int lrow = l & 15, lk8 = (l >> 4) * 8;
  const int r = r0 + w * 16 + lrow;
  const int t = r >> 6, b = r & 63;
  const int tok = sents[b * T_ + (dir ? (T_ - 1 - t) : t)];
  const float* arow = emb + (size_t)tok * E_;

  f4 acc[4];
  #pragma unroll
  for (int i = 0; i < 4; i++){ acc[i][0]=0.f; acc[i][1]=0.f; acc[i][2]=0.f; acc[i][3]=0.f; }

  for (int ks = 0; ks < 8; ks++){
    const float* ap = arow + ks * 32 + lk8;
    f4 v0 = *(const f4*)ap;
    f4 v1 = *(const f4*)(ap + 4);
    bf8 ah, al;
    #pragma unroll
    for (int j = 0; j < 4; j++){
      ushort hh, ll;
      splitf(v0[j], hh, ll); ah[j] = (short)hh; al[j] = (short)ll;
      splitf(v1[j], hh, ll); ah[4 + j] = (short)hh; al[4 + j] = (short)ll;
    }
    const int kc = ks * 4 + (l >> 4);
    #pragma unroll
    for (int nt = 0; nt < 4; nt++){
      const int c = nt * 16 + lrow;
      const int skc = kc ^ (c & 31);
      bf8 bh = *(const bf8*)&Bs[0][c][skc * 8];
      bf8 blo = *(const bf8*)&Bs[1][c][skc * 8];
      acc[nt] = mfma16(ah, bh, acc[nt]);
      acc[nt] = mfma16(ah, blo, acc[nt]);
      acc[nt] = mfma16(al, bh, acc[nt]);
    }
  }

  const float* bih = dir ? bihB : bihF;
  const float* bhh = dir ? bhhB : bhhF;
  #pragma unroll
  for (int nt = 0; nt < 4; nt++){
    int col = n0 + nt * 16 + lrow;       // gate-major column in [0,1024)
    float bias = bih[col] + bhh[col];
    int gate = col >> 8, un = col & 255;
    size_t plane = (size_t)(dir * 16 + (un >> 4));
    int u15 = un & 15;
    #pragma unroll
    for (int reg = 0; reg < 4; reg++){
      int row = r0 + w * 16 + (l >> 4) * 4 + reg;
      int tt = row >> 6, bb = row & 63;
      gx[((plane * 256 + tt) * 64 + bb) * 64 + gate * 16 + u15] = acc[nt][reg] + bias;
    }
  }
}

// ============ K2: persistent recurrence, flag barrier + IC-coherent h ============
__global__ __launch_bounds__(256) void k2_persist(const ushort* __restrict__ q,
    const float* __restrict__ gx, const float* __restrict__ c0,
    ushort* __restrict__ hsHi, ushort* __restrict__ hsLo, uint* __restrict__ flags)
{
  __shared__ ushort Bs[2][64][256];
  const int tid = threadIdx.x;
  const int bid = blockIdx.x;
  const int dir = bid >> 4;
  const int ub = bid & 15;          // block index within dir
  const int u0 = ub * 16;
  const ushort* whi = q + (dir ? WHHB_HI : WHHF_HI);

  for (int cid = tid; cid < 4096; cid += 256){
    int half = cid >> 11;
    int c = (cid >> 5) & 63;
    int kc = cid & 31;
    int grow = (c >> 4) * 256 + u0 + (c & 15); // gate-strided rows
    const ushort* src = whi + half * LO_D + (size_t)grow * 256 + kc * 8;
    uint4 v = *(const uint4*)src;
    *(uint4*)&Bs[half][c][(kc ^ (c & 31)) * 8] = v;
  }
  __syncthreads();

  const int w = tid >> 6, l = tid & 63;
  const int lrow = l & 15, lk8 = (l >> 4) * 8;
  const int arow = w * 16 + lrow;
  const int unit = u0 + lrow;
  const int erow = w * 16 + (l >> 4) * 4;

  float creg[4];
  #pragma unroll
  for (int reg = 0; reg < 4; reg++)
    creg[reg] = c0[dir * 16384 + (erow + reg) * 256 + unit];

  const float* gxp = gx + (size_t)(dir * 16 + ub) * (256ull * 4096ull);
  ushort* hHiD = hsHi + (size_t)dir * HS_DIR;
  ushort* hLoD = hsLo + (size_t)dir * HS_DIR;
  uint* fb = flags + dir * 1024;

  for (int t = 0; t < T_; t++){
    // prefetch gate inputs (independent of hprev) — overlaps any residual spin
    float gv[4][4];
    #pragma unroll
    for (int reg = 0; reg < 4; reg++)
      #pragma unroll
      for (int gate = 0; gate < 4; gate++)
        gv[reg][gate] = gxp[((size_t)t * 64 + (erow + reg)) * 64 + gate * 16 + lrow];

    // batch-load this wave's h fragments (IC-coherent, bypass L1/L2)
    const ushort* rowHi = hHiD + (size_t)t * 16384 + arow * 256 + lk8;
    const ushort* rowLo = hLoD + (size_t)t * 16384 + arow * 256 + lk8;
    bf8 ah[8], al[8];
    LD16(ah[0], rowHi, 0);   LD16(al[0], rowLo, 0);
    LD16(ah[1], rowHi, 64);  LD16(al[1], rowLo, 64);
    LD16(ah[2], rowHi, 128); LD16(al[2], rowLo, 128);
    LD16(ah[3], rowHi, 192); LD16(al[3], rowLo, 192);
    LD16(ah[4], rowHi, 256); LD16(al[4], rowLo, 256);
    LD16(ah[5], rowHi, 320); LD16(al[5], rowLo, 320);
    LD16(ah[6], rowHi, 384); LD16(al[6], rowLo, 384);
    LD16(ah[7], rowHi, 448); LD16(al[7], rowLo, 448);
    asm volatile("s_waitcnt vmcnt(0)" ::: "memory");
    __builtin_amdgcn_sched_barrier(0);

    f4 acc[4];
    #pragma unroll
    for (int i = 0; i < 4; i++){ acc[i][0]=0.f; acc[i][1]=0.f; acc[i][2]=0.f; acc[i][3]=0.f; }

    #pragma unroll
    for (int ks = 0; ks < 8; ks++){
      const int kc = ks * 4 + (l >> 4);
      #pragma unroll
      for (int nt = 0; nt < 4; nt++){
        const int c = nt * 16 + lrow;
        const int skc = kc ^ (c & 31);
        bf8 bh  = *(const bf8*)&Bs[0][c][skc * 8];
        bf8 blo = *(const bf8*)&Bs[1][c][skc * 8];
        acc[nt] = mfma16(ah[ks], bh, acc[nt]);
        acc[nt] = mfma16(ah[ks], blo, acc[nt]);
        acc[nt] = mfma16(al[ks], bh, acc[nt]);
      }
    }

    // epilogue: gates -> c,h update; IC-coherent h stores
    ushort* oHi = hHiD + (size_t)(t + 1) * 16384 + erow * 256 + unit;
    ushort* oLo = hLoD + (size_t)(t + 1) * 16384 + erow * 256 + unit;
    ushort hh_[4], ll_[4];
    #pragma unroll
    for (int reg = 0; reg < 4; reg++){
      float g0 = acc[0][reg] + gv[reg][0];
      float g1 = acc[1][reg] + gv[reg][1];
      float g2 = acc[2][reg] + gv[reg][2];
      float g3 = acc[3][reg] + gv[reg][3];
      float cn = sigm(g1) * creg[reg] + sigm(g0) * tanhf(g2);
      float hn = sigm(g3) * tanhf(cn);
      creg[reg] = cn;
      splitf(hn, hh_[reg], ll_[reg]);
    }
    ST2(oHi, 0, hh_[0]);    ST2(oLo, 0, ll_[0]);
    ST2(oHi, 512, hh_[1]);  ST2(oLo, 512, ll_[1]);
    ST2(oHi, 1024, hh_[2]); ST2(oLo, 1024, ll_[2]);
    ST2(oHi, 1536, hh_[3]); ST2(oLo, 1536, ll_[3]);

    if (t + 1 < T_){
      // ---- fence-free per-dir barrier via IC-homed flags ----
      asm volatile("s_waitcnt vmcnt(0)" ::: "memory"); // own stores at IC
      __syncthreads();                                  // whole block done
      if (tid == 0)
        __hip_atomic_store(&fb[ub * 16], (uint)(t + 1), __ATOMIC_RELAXED,
                           __HIP_MEMORY_SCOPE_AGENT);
      if (w == 0){
        uint e = (uint)(t + 1);
        uint fv;
        do {
          fv = (l < 16) ? __hip_atomic_load(&fb[(l & 15) * 16], __ATOMIC_RELAXED,
                                            __HIP_MEMORY_SCOPE_AGENT)
                        : 0xffffffffu;
        } while (!__all(fv >= e));
      }
      __syncthreads();
      __builtin_amdgcn_sched_barrier(0);
    }
  }
}

// ============ K3: logits = [hf|hb] @ WlT + bl (consumes pre-split h) ============
__global__ __launch_bounds__(256) void k3_logits(const ushort* __restrict__ q,
    const float* __restrict__ bl, float* __restrict__ logits)
{
  __shared__ ushort Bs[2][32][512];
  const int tid = threadIdx.x;
  const int r0 = blockIdx.x * 64;
  const ushort* hsHi = q + HS_HI;
  const ushort* hsLo = q + HS_LO;

  for (int cid = tid; cid < 4096; cid += 256){
    int half = cid >> 11;
    int c = (cid >> 6) & 31;
    int kc = cid & 63;
    uint4 v; v.x = 0; v.y = 0; v.z = 0; v.w = 0;
    if (c < NTAG){
      const ushort* src = q + (half ? WL_LO : WL_HI) + (size_t)c * 512 + kc * 8;
      v = *(const uint4*)src;
    }
    *(uint4*)&Bs[half][c][(kc ^ (c & 31)) * 8] = v;
  }
  __syncthreads();

  const int w = tid >> 6, l = tid & 63;
  const int lrow = l & 15, lk8 = (l >> 4) * 8;
  const int r = r0 + w * 16 + lrow;
  const int t = r >> 6, b = r & 63;

  f4 acc[2];
  #pragma unroll
  for (int i = 0; i < 2; i++){ acc[i][0]=0.f; acc[i][1]=0.f; acc[i][2]=0.f; acc[i][3]=0.f; }

  for (int ks = 0; ks < 16; ks++){
    int k = ks * 32 + lk8;
    size_t off;
    if (k < 256)
      off = (size_t)(t + 1) * 16384 + (size_t)b * 256 + k;                    // hf slot t+1
    else
      off = HS_DIR + (size_t)(256 - t) * 16384 + (size_t)b * 256 + (k - 256); // hb slot 256-t
    bf8 ah = *(const bf8*)&hsHi[off];
    bf8 al = *(const bf8*)&hsLo[off];
    int kc = k >> 3;
    #pragma unroll
    for (int nt = 0; nt < 2; nt++){
      int c = nt * 16 + lrow;
      int skc = kc ^ (c & 31);
      bf8 bh  = *(const bf8*)&Bs[0][c][skc * 8];
      bf8 blo = *(const bf8*)&Bs[1][c][skc * 8];
      acc[nt] = mfma16(ah, bh, acc[nt]);
      acc[nt] = mfma16(ah, blo, acc[nt]);
      acc[nt] = mfma16(al, bh, acc[nt]);
    }
  }

  #pragma unroll
  for (int nt = 0; nt < 2; nt++){
    int tag = nt * 16 + lrow;
    if (tag < NTAG){
      float bias = bl[tag];
      #pragma unroll
      for (int reg = 0; reg < 4; reg++){
        int row = r0 + w * 16 + (l >> 4) * 4 + reg;
        logits[(size_t)row * NTAG + tag] = acc[nt][reg] + bias;
      }
    }
  }
}

// ============ K4: Viterbi DP + backtrace + probs + scores ============
__global__ __launch_bounds__(64) void k4_viterbi(const float* __restrict__ logits,
    const float* __restrict__ trans, float* __restrict__ out)
{
  const int b = blockIdx.x, tid = threadIdx.x;
  __shared__ float tr[NTAG][NTAG];
  __shared__ float trell[T_][NTAG];
  __shared__ unsigned char bp[T_][NTAG];
  __shared__ int path[T_];
  __shared__ float cur[NTAG], nv[NTAG];

  for (int i = tid; i < NTAG * NTAG; i += 64) tr[i / NTAG][i % NTAG] = trans[i];
  if (tid < NTAG){
    float v = logits[(size_t)b * NTAG + tid];
    cur[tid] = v; trell[0][tid] = v;
  }
  __syncthreads();

  for (int t = 1; t < T_; t++){
    if (tid < NTAG){
      float best = -3.0e38f; int bi = 0;
      #pragma unroll
      for (int p = 0; p < NTAG; p++){
        float v = cur[p] + tr[p][tid];
        if (v > best){ best = v; bi = p; }   // first-max (strict >)
      }
      float nvv = logits[((size_t)t * 64 + b) * NTAG + tid] + best;
      nv[tid] = nvv; trell[t][tid] = nvv; bp[t][tid] = (unsigned char)bi;
    }
    __syncthreads();
    if (tid < NTAG) cur[tid] = nv[tid];
    __syncthreads();
  }

  if (tid == 0){
    float best = -3.0e38f; int bi = 0;
    for (int c = 0; c < NTAG; c++){
      if (trell[T_ - 1][c] > best){ best = trell[T_ - 1][c]; bi = c; }
    }
    out[b] = best;                 // scores
    path[T_ - 1] = bi;
    for (int t = T_ - 1; t >= 1; t--) path[t - 1] = bp[t][path[t]];
  }
  __syncthreads();

  for (int t = tid; t < T_; t += 64){
    float m = -3.0e38f;
    for (int c = 0; c < NTAG; c++) m = fmaxf(m, trell[t][c]);
    float s = 0.f;
    for (int c = 0; c < NTAG; c++) s += expf(trell[t][c] - m);
    float p = expf(trell[t][path[t]] - m) / s;
    out[64 + (size_t)b * T_ + t] = (float)path[t];          // path.T
    out[64 + 64 * T_ + (size_t)b * T_ + t] = p;             // probs.T
  }
}

extern "C" void kernel_launch(void* const* d_in, const int* in_sizes, int n_in,
                              void* d_out, int out_size, void* d_ws, size_t ws_size,
                              hipStream_t stream){
  (void)in_sizes; (void)n_in; (void)out_size; (void)ws_size;
  const int*   sents = (const int*)d_in[0];
  const float* emb   = (const float*)d_in[1];
  const float* wihF  = (const float*)d_in[2];
  const float* whhF  = (const float*)d_in[3];
  const float* bihF  = (const float*)d_in[4];
  const float* bhhF  = (const float*)d_in[5];
  const float* wihB  = (const float*)d_in[6];
  const float* whhB  = (const float*)d_in[7];
  const float* bihB  = (const float*)d_in[8];
  const float* bhhB  = (const float*)d_in[9];
  const float* wl    = (const float*)d_in[10];
  const float* bl    = (const float*)d_in[11];
  const float* trans = (const float*)d_in[12];
  const float* h0    = (const float*)d_in[13];
  const float* c0    = (const float*)d_in[14];

  float* wsf    = (float*)d_ws;
  ushort* q     = (ushort*)(wsf + Q_OFFF);
  float* gx     = wsf + GX_OFF;
  float* logits = wsf + LG_OFF;
  uint* flags   = (uint*)(wsf + FLG_OFF);
  float* out    = (float*)d_out;
  ushort* hsHi  = q + HS_HI;
  ushort* hsLo  = q + HS_LO;

  k0_split<<<1024, 256, 0, stream>>>(whhF, whhB, wihF, wihB, wl, h0, q, flags);
  k1_gx<<<dim3(16, 256, 2), 256, 0, stream>>>(sents, emb, q, bihF, bhhF, bihB, bhhB, gx);

  {
    const ushort* qa = q; const float* gxa = gx; const float* c0a = c0;
    ushort* hia = hsHi; ushort* loa = hsLo; uint* fla = flags;
    void* args[] = { (void*)&qa, (void*)&gxa, (void*)&c0a,
                     (void*)&hia, (void*)&loa, (void*)&fla };
    hipLaunchCooperativeKernel((const void*)k2_persist, dim3(32), dim3(256),
                               args, 0, stream);
  }

  k3_logits<<<256, 256, 0, stream>>>(q, bl, logits);
  k4_viterbi<<<64, 64, 0, stream>>>(logits, trans, out);
}

// Round 6
// 1588.269 us; speedup vs baseline: 2.4039x; 1.0855x over previous
//
#include <hip/hip_runtime.h>

typedef unsigned int uint;
typedef unsigned short ushort;
typedef __attribute__((ext_vector_type(4))) float f4;
typedef __attribute__((ext_vector_type(8))) short bf8;

#define T_ 256
#define B_ 64
#define E_ 256
#define HD_ 256
#define NTAG 20

// ---- workspace layout (float offsets) ----
#define GX_OFF 0ull           // gx planes [2*16][256 t][256 ctid][16]  (33,554,432 f)
#define LG_OFF 33554432ull    // logits [256*64][20] (327,680 f)
#define FLG_OFF 33882112ull   // flags: dir0 @0..255, ectl @512..520, dir1 @1024..1279
#define Q_OFFF 33884160ull    // ushort area starts here

// ---- q (ushort) offsets ----
#define WHHF_HI 0u
#define WHHB_HI 524288u
#define WIHF_HI 1048576u
#define WIHB_HI 1572864u
#define LO_D    262144u       // lo = hi + LO_D for the 4 weight matrices
#define WL_HI   2097152u
#define WL_LO   2107392u
#define HS_HI   2117632u      // h hi-planes [2 dir][257 slot][64 row][256 u]
#define HS_LO   10539008u     // h lo-planes same shape
#define HS_DIR  4210688ull    // per-dir stride (257*16384)

#define ECTL_CNT 512u         // flags[512+xcc] = per-XCD ticket counter
#define ECTL_LDR 520u         // flags[520] = leader xcc (0xffffffff = unset)

__device__ __forceinline__ ushort f2bf(float x){
  uint u = __float_as_uint(x);
  uint r = (u + 0x7fffu + ((u >> 16) & 1u)) >> 16;
  return (ushort)r;
}
__device__ __forceinline__ float bf2f(ushort h){ return __uint_as_float(((uint)h) << 16); }
__device__ __forceinline__ void splitf(float x, ushort &h, ushort &l){
  h = f2bf(x);
  l = f2bf(x - bf2f(h));
}
__device__ __forceinline__ f4 mfma16(bf8 a, bf8 b, f4 c){
  return __builtin_amdgcn_mfma_f32_16x16x32_bf16(a, b, c, 0, 0, 0);
}
__device__ __forceinline__ float sigm(float x){ return 1.0f / (1.0f + expf(-x)); }

// XCD-local (same-L2) 16B load: bypass L1 only, served by the shared L2.
#define LDH(dst, base, off) \
  asm volatile("global_load_dwordx4 %0, %1, off offset:" #off " sc0" \
               : "=v"(dst) : "v"(base))
// normal cached 16B load (gx is read-once streaming)
#define LDG16(dst, base, off) \
  asm volatile("global_load_dwordx4 %0, %1, off offset:" #off \
               : "=v"(dst) : "v"(base))
// XCD-local 2B store: write-through L1 into shared L2.
#define ST2(base, off, val) \
  asm volatile("global_store_short %0, %1, off offset:" #off " sc0" \
               :: "v"(base), "v"(val) : "memory")
#define STFLAG(p, v) \
  asm volatile("global_store_dword %0, %1, off sc0" :: "v"(p), "v"(v) : "memory")

// ============ K0: split weights + h0 into bf16 hi/lo; reset flags + election ============
__global__ void k0_split(const float* __restrict__ whhF, const float* __restrict__ whhB,
                         const float* __restrict__ wihF, const float* __restrict__ wihB,
                         const float* __restrict__ wl, const float* __restrict__ h0,
                         ushort* __restrict__ q, uint* __restrict__ flags){
  uint stride = gridDim.x * blockDim.x;
  for (uint i = blockIdx.x * blockDim.x + threadIdx.x; i < 1093632u; i += stride){
    float x; uint hbase;
    if (i < 262144u){ x = whhF[i]; hbase = WHHF_HI + i; }
    else if (i < 524288u){ x = whhB[i - 262144u]; hbase = WHHB_HI + (i - 262144u); }
    else if (i < 786432u){ x = wihF[i - 524288u]; hbase = WIHF_HI + (i - 524288u); }
    else if (i < 1048576u){ x = wihB[i - 786432u]; hbase = WIHB_HI + (i - 786432u); }
    else if (i < 1058816u){
      uint j = i - 1048576u; // < 10240
      ushort h, l; splitf(wl[j], h, l);
      q[WL_HI + j] = h; q[WL_LO + j] = l;
      continue;
    } else if (i < 1091584u){
      uint j = i - 1058816u; // < 32768: h0[2][64][256] -> slot 0 per dir
      uint dir = j >> 14, rem = j & 16383u;
      ushort h, l; splitf(h0[j], h, l);
      q[HS_HI + dir * (uint)HS_DIR + rem] = h;
      q[HS_LO + dir * (uint)HS_DIR + rem] = l;
      continue;
    } else {
      uint j = i - 1091584u; // < 2048
      __hip_atomic_store(&flags[j], (j == ECTL_LDR) ? 0xffffffffu : 0u,
                         __ATOMIC_RELAXED, __HIP_MEMORY_SCOPE_AGENT);
      continue;
    }
    ushort h, l; splitf(x, h, l);
    q[hbase] = h; q[hbase + LO_D] = l;
  }
}

// ============ K1: gx = x @ WihT + bih + bhh, per-(dir,ugrp,thread) contiguous 16f ============
__global__ __launch_bounds__(256) void k1_gx(const int* __restrict__ sents,
    const float* __restrict__ emb, const ushort* __restrict__ q,
    const float* __restrict__ bihF, const float* __restrict__ bhhF,
    const float* __restrict__ bihB, const float* __restrict__ bhhB,
    float* __restrict__ gx)
{
  __shared__ ushort Bs[2][64][256]; // 64 KiB, XOR-swizzled 16B chunks
  const int tid = threadIdx.x;
  const int dir = blockIdx.z;
  const int n0 = blockIdx.x * 64;
  const int r0 = blockIdx.y * 64;
  const ushort* whi = q + (dir ? WIHB_HI : WIHF_HI);

  for (int cid = tid; cid < 4096; cid += 256){
    int half = cid >> 11;
    int c = (cid >> 5) & 63;
    int kc = cid & 31;
    const ushort* src = whi + half * LO_D + (size_t)(n0 + c) * 256 + kc * 8;
    uint4 v = *(const uint4*)src;
    *(uint4*)&Bs[half][c][(kc ^ (c & 31)) * 8] = v;
  }
  __syncthreads();

  const int w = tid >> 6, l = tid & 63;
  const int lrow = l & 15, lk8 = (l >> 4) * 8;
  const int r = r0 + w * 16 + lrow;
  const int t = r >> 6, b = r & 63;
  const int tok = sents[b * T_ + (dir ? (T_ - 1 - t) : t)];
  const float* arow = emb + (size_t)tok * E_;

  f4 acc[4];
  #pragma unroll
  for (int i = 0; i < 4; i++){ acc[i][0]=0.f; acc[i][1]=0.f; acc[i][2]=0.f; acc[i][3]=0.f; }

  for (int ks = 0; ks < 8; ks++){
    const float* ap = arow + ks * 32 + lk8;
    f4 v0 = *(const f4*)ap;
    f4 v1 = *(const f4*)(ap + 4);
    bf8 ah, al;
    #pragma unroll
    for (int j = 0; j < 4; j++){
      ushort hh, ll;
      splitf(v0[j], hh, ll); ah[j] = (short)hh; al[j] = (short)ll;
      splitf(v1[j], hh, ll); ah[4 + j] = (short)hh; al[4 + j] = (short)ll;
    }
    const int kc = ks * 4 + (l >> 4);
    #pragma unroll
    for (int nt = 0; nt < 4; nt++){
      const int c = nt * 16 + lrow;
      const int skc = kc ^ (c & 31);
      bf8 bh = *(const bf8*)&Bs[0][c][skc * 8];
      bf8 blo = *(const bf8*)&Bs[1][c][skc * 8];
      acc[nt] = mfma16(ah, bh, acc[nt]);
      acc[nt] = mfma16(ah, blo, acc[nt]);
      acc[nt] = mfma16(al, bh, acc[nt]);
    }
  }

  const float* bih = dir ? bihB : bihF;
  const float* bhh = dir ? bhhB : bhhF;
  #pragma unroll
  for (int nt = 0; nt < 4; nt++){
    int col = n0 + nt * 16 + lrow;       // gate-major column in [0,1024)
    float bias = bih[col] + bhh[col];
    int gate = col >> 8, ug = (col >> 4) & 15;
    #pragma unroll
    for (int reg = 0; reg < 4; reg++){
      int row = r0 + w * 16 + (l >> 4) * 4 + reg;
      int tt = row >> 6, b2 = row & 63;
      int ctid = ((b2 >> 4) << 6) | (((b2 >> 2) & 3) << 4) | lrow;
      gx[(((size_t)(dir * 16 + ug) * 256 + tt) * 256 + ctid) * 16
         + (b2 & 3) * 4 + gate] = acc[nt][reg] + bias;
    }
  }
}

// ============ K2: persistent recurrence on ONE XCD (election + L2-local sync) ============

#define K2_STEP(TT, GC)                                                             \
{                                                                                   \
  const int t_ = (TT);                                                              \
  asm volatile("s_waitcnt vmcnt(4)" ::: "memory");                                  \
  __builtin_amdgcn_sched_barrier(0);                                                \
  f4 acc[4];                                                                        \
  _Pragma("unroll")                                                                 \
  for (int i = 0; i < 4; i++){ acc[i][0]=0.f; acc[i][1]=0.f; acc[i][2]=0.f; acc[i][3]=0.f; } \
  _Pragma("unroll")                                                                 \
  for (int ks = 0; ks < 8; ks++){                                                   \
    const int kc = ks * 4 + (l >> 4);                                               \
    _Pragma("unroll")                                                               \
    for (int nt = 0; nt < 4; nt++){                                                 \
      const int c = nt * 16 + lrow;                                                 \
      const int skc = kc ^ (c & 31);                                                \
      bf8 bh  = *(const bf8*)&Bs[0][c][skc * 8];                                    \
      bf8 blo = *(const bf8*)&Bs[1][c][skc * 8];                                    \
      acc[nt] = mfma16(ah[ks], bh, acc[nt]);                                        \
      acc[nt] = mfma16(ah[ks], blo, acc[nt]);                                       \
      acc[nt] = mfma16(al[ks], bh, acc[nt]);                                        \
    }                                                                               \
  }                                                                                 \
  {                                                                                 \
    ushort* oHi = hHiD + (size_t)(t_ + 1) * 16384 + erow * 256 + unit;              \
    ushort* oLo = hLoD + (size_t)(t_ + 1) * 16384 + erow * 256 + unit;              \
    ushort hh_[4], ll_[4];                                                          \
    _Pragma("unroll")                                                               \
    for (int reg = 0; reg < 4; reg++){                                              \
      float g0 = acc[0][reg] + GC[reg][0];                                          \
      float g1 = acc[1][reg] + GC[reg][1];                                          \
      float g2 = acc[2][reg] + GC[reg][2];                                          \
      float g3 = acc[3][reg] + GC[reg][3];                                          \
      float cn = sigm(g1) * creg[reg] + sigm(g0) * tanhf(g2);                       \
      float hn = sigm(g3) * tanhf(cn);                                              \
      creg[reg] = cn;                                                               \
      splitf(hn, hh_[reg], ll_[reg]);                                               \
    }                                                                               \
    ST2(oHi, 0, hh_[0]);    ST2(oLo, 0, ll_[0]);                                    \
    ST2(oHi, 512, hh_[1]);  ST2(oLo, 512, ll_[1]);                                  \
    ST2(oHi, 1024, hh_[2]); ST2(oLo, 1024, ll_[2]);                                 \
    ST2(oHi, 1536, hh_[3]); ST2(oLo, 1536, ll_[3]);                                 \
  }                                                                                 \
  if (t_ + 1 < T_){                                                                 \
    asm volatile("s_waitcnt vmcnt(0)" ::: "memory");                                \
    __builtin_amdgcn_sched_barrier(0);                                              \
    __syncthreads();                                                                \
    uint e = (uint)(t_ + 1);                                                        \
    if (tid == 0) STFLAG(fb + (ub << 4), e);                                        \
    if (w == 0){                                                                    \
      uint fv = 0xffffffffu;                                                        \
      const uint* fp = fb + ((l & 15) << 4);                                        \
      int guard = 0;                                                                \
      do {                                                                          \
        if (l < 16) asm volatile("global_load_dword %0, %1, off sc0"                \
                                 : "=v"(fv) : "v"(fp));                             \
        asm volatile("s_waitcnt vmcnt(0)" ::: "memory");                            \
      } while (!__all(fv >= e) && ++guard < 16384);                                 \
    }                                                                               \
    __syncthreads();                                                                \
    __builtin_amdgcn_sched_barrier(0);                                              \
    const ushort* rh = hHiD + (size_t)(t_ + 1) * 16384 + arow * 256 + lk8;          \
    const ushort* rl = hLoD + (size_t)(t_ + 1) * 16384 + arow * 256 + lk8;          \
    LDH(ah[0], rh, 0);   LDH(ah[1], rh, 64);  LDH(ah[2], rh, 128); LDH(ah[3], rh, 192); \
    LDH(ah[4], rh, 256); LDH(ah[5], rh, 320); LDH(ah[6], rh, 384); LDH(ah[7], rh, 448); \
    LDH(al[0], rl, 0);   LDH(al[1], rl, 64);  LDH(al[2], rl, 128); LDH(al[3], rl, 192); \
    LDH(al[4], rl, 256); LDH(al[5], rl, 320); LDH(al[6], rl, 384); LDH(al[7], rl, 448); \
    int t2 = (t_ + 2 < T_) ? (t_ + 2) : (T_ - 1);                                   \
    const float* pn = gxp + ((size_t)t2 * 256 + tid) * 16;                          \
    LDG16(GC[0], pn, 0); LDG16(GC[1], pn, 16);                                      \
    LDG16(GC[2], pn, 32); LDG16(GC[3], pn, 48);                                     \
  }                                                                                 \
}

__global__ __launch_bounds__(256, 1) void k2_persist(const ushort* __restrict__ q,
    const float* __restrict__ gx, const float* __restrict__ c0,
    ushort* __restrict__ hsHi, ushort* __restrict__ hsLo, uint* __restrict__ flags)
{
  __shared__ ushort Bs[2][64][256];      // 64 KiB (proven-safe size)
  __shared__ int s_tk;
  const int tid = threadIdx.x;

  // ---- election: first XCD to assemble 32 blocks wins; its tickets 0..31 work ----
  if (tid == 0){
    uint xcc;
    asm volatile("s_getreg_b32 %0, hwreg(HW_REG_XCC_ID)" : "=s"(xcc));
    xcc &= 7u;
    uint my = atomicAdd(&flags[ECTL_CNT + xcc], 1u);
    if (my == 31u) atomicCAS(&flags[ECTL_LDR], 0xffffffffu, xcc);
    uint L = 0xffffffffu;
    for (int g = 0; g < (1 << 20); ++g){
      L = __hip_atomic_load(&flags[ECTL_LDR], __ATOMIC_RELAXED,
                            __HIP_MEMORY_SCOPE_AGENT);
      if (L != 0xffffffffu) break;
    }
    s_tk = (L == xcc && my < 32u) ? (int)my : -1;
  }
  __syncthreads();
  const int ticket = s_tk;
  if (ticket < 0) return;

  const int dir = ticket >> 4;           // 0..1
  const int ub  = ticket & 15;           // unit-group within dir
  const int u0  = ub * 16;
  const ushort* whi = q + (dir ? WHHB_HI : WHHF_HI);

  for (int cid = tid; cid < 4096; cid += 256){
    int half = cid >> 11;
    int c = (cid >> 5) & 63;
    int kc = cid & 31;
    int grow = (c >> 4) * 256 + u0 + (c & 15); // gate-strided rows
    const ushort* src = whi + half * LO_D + (size_t)grow * 256 + kc * 8;
    uint4 v = *(const uint4*)src;
    *(uint4*)&Bs[half][c][(kc ^ (c & 31)) * 8] = v;
  }
  __syncthreads();

  const int w = tid >> 6, l = tid & 63;
  const int lrow = l & 15, lk8 = (l >> 4) * 8;
  const int arow = w * 16 + lrow;
  const int unit = u0 + lrow;
  const int erow = w * 16 + (l >> 4) * 4;

  float creg[4];
  #pragma unroll
  for (int reg = 0; reg < 4; reg++)
    creg[reg] = c0[dir * 16384 + (erow + reg) * 256 + unit];
  asm volatile("" :: "v"(creg[0]), "v"(creg[1]), "v"(creg[2]), "v"(creg[3]));

  ushort* hHiD = hsHi + (size_t)dir * HS_DIR;
  ushort* hLoD = hsLo + (size_t)dir * HS_DIR;
  const float* gxp = gx + (size_t)(dir * 16 + ub) * 1048576ull;
  uint* fb = flags + dir * 1024;

  f4 ga[4], gb[4];
  bf8 ah[8], al[8];

  // prologue: gv(0)->ga, h(0), gv(1)->gb (order matters for vmcnt(4) at first top)
  {
    const float* p0 = gxp + (size_t)tid * 16;
    LDG16(ga[0], p0, 0); LDG16(ga[1], p0, 16); LDG16(ga[2], p0, 32); LDG16(ga[3], p0, 48);
    const ushort* rh = hHiD + arow * 256 + lk8;
    const ushort* rl = hLoD + arow * 256 + lk8;
    LDH(ah[0], rh, 0);   LDH(ah[1], rh, 64);  LDH(ah[2], rh, 128); LDH(ah[3], rh, 192);
    LDH(ah[4], rh, 256); LDH(ah[5], rh, 320); LDH(ah[6], rh, 384); LDH(ah[7], rh, 448);
    LDH(al[0], rl, 0);   LDH(al[1], rl, 64);  LDH(al[2], rl, 128); LDH(al[3], rl, 192);
    LDH(al[4], rl, 256); LDH(al[5], rl, 320); LDH(al[6], rl, 384); LDH(al[7], rl, 448);
    const float* p1 = gxp + ((size_t)256 + tid) * 16;
    LDG16(gb[0], p1, 0); LDG16(gb[1], p1, 16); LDG16(gb[2], p1, 32); LDG16(gb[3], p1, 48);
  }

  #pragma unroll 1
  for (int t = 0; t < T_; t += 2){
    K2_STEP(t, ga);
    K2_STEP(t + 1, gb);
  }
  asm volatile("s_waitcnt vmcnt(0)" ::: "memory");
}

// ============ K3: logits = [hf|hb] @ WlT + bl (consumes pre-split h) ============
__global__ __launch_bounds__(256) void k3_logits(const ushort* __restrict__ q,
    const float* __restrict__ bl, float* __restrict__ logits)
{
  __shared__ ushort Bs[2][32][512];
  const int tid = threadIdx.x;
  const int r0 = blockIdx.x * 64;
  const ushort* hsHi = q + HS_HI;
  const ushort* hsLo = q + HS_LO;

  for (int cid = tid; cid < 4096; cid += 256){
    int half = cid >> 11;
    int c = (cid >> 6) & 31;
    int kc = cid & 63;
    uint4 v; v.x = 0; v.y = 0; v.z = 0; v.w = 0;
    if (c < NTAG){
      const ushort* src = q + (half ? WL_LO : WL_HI) + (size_t)c * 512 + kc * 8;
      v = *(const uint4*)src;
    }
    *(uint4*)&Bs[half][c][(kc ^ (c & 31)) * 8] = v;
  }
  __syncthreads();

  const int w = tid >> 6, l = tid & 63;
  const int lrow = l & 15, lk8 = (l >> 4) * 8;
  const int r = r0 + w * 16 + lrow;
  const int t = r >> 6, b = r & 63;

  f4 acc[2];
  #pragma unroll
  for (int i = 0; i < 2; i++){ acc[i][0]=0.f; acc[i][1]=0.f; acc[i][2]=0.f; acc[i][3]=0.f; }

  for (int ks = 0; ks < 16; ks++){
    int k = ks * 32 + lk8;
    size_t off;
    if (k < 256)
      off = (size_t)(t + 1) * 16384 + (size_t)b * 256 + k;                    // hf slot t+1
    else
      off = HS_DIR + (size_t)(256 - t) * 16384 + (size_t)b * 256 + (k - 256); // hb slot 256-t
    bf8 ah = *(const bf8*)&hsHi[off];
    bf8 al = *(const bf8*)&hsLo[off];
    int kc = k >> 3;
    #pragma unroll
    for (int nt = 0; nt < 2; nt++){
      int c = nt * 16 + lrow;
      int skc = kc ^ (c & 31);
      bf8 bh  = *(const bf8*)&Bs[0][c][skc * 8];
      bf8 blo = *(const bf8*)&Bs[1][c][skc * 8];
      acc[nt] = mfma16(ah, bh, acc[nt]);
      acc[nt] = mfma16(ah, blo, acc[nt]);
      acc[nt] = mfma16(al, bh, acc[nt]);
    }
  }

  #pragma unroll
  for (int nt = 0; nt < 2; nt++){
    int tag = nt * 16 + lrow;
    if (tag < NTAG){
      float bias = bl[tag];
      #pragma unroll
      for (int reg = 0; reg < 4; reg++){
        int row = r0 + w * 16 + (l >> 4) * 4 + reg;
        logits[(size_t)row * NTAG + tag] = acc[nt][reg] + bias;
      }
    }
  }
}

// ============ K4: Viterbi DP + backtrace + probs + scores ============
__global__ __launch_bounds__(64) void k4_viterbi(const float* __restrict__ logits,
    const float* __restrict__ trans, float* __restrict__ out)
{
  const int b = blockIdx.x, tid = threadIdx.x;
  __shared__ float tr[NTAG][NTAG];
  __shared__ float trell[T_][NTAG];
  __shared__ unsigned char bp[T_][NTAG];
  __shared__ int path[T_];
  __shared__ float cur[NTAG], nv[NTAG];

  for (int i = tid; i < NTAG * NTAG; i += 64) tr[i / NTAG][i % NTAG] = trans[i];
  if (tid < NTAG){
    float v = logits[(size_t)b * NTAG + tid];
    cur[tid] = v; trell[0][tid] = v;
  }
  __syncthreads();

  for (int t = 1; t < T_; t++){
    if (tid < NTAG){
      float best = -3.0e38f; int bi = 0;
      #pragma unroll
      for (int p = 0; p < NTAG; p++){
        float v = cur[p] + tr[p][tid];
        if (v > best){ best = v; bi = p; }   // first-max (strict >)
      }
      float nvv = logits[((size_t)t * 64 + b) * NTAG + tid] + best;
      nv[tid] = nvv; trell[t][tid] = nvv; bp[t][tid] = (unsigned char)bi;
    }
    __syncthreads();
    if (tid < NTAG) cur[tid] = nv[tid];
    __syncthreads();
  }

  if (tid == 0){
    float best = -3.0e38f; int bi = 0;
    for (int c = 0; c < NTAG; c++){
      if (trell[T_ - 1][c] > best){ best = trell[T_ - 1][c]; bi = c; }
    }
    out[b] = best;                 // scores
    path[T_ - 1] = bi;
    for (int t = T_ - 1; t >= 1; t--) path[t - 1] = bp[t][path[t]];
  }
  __syncthreads();

  for (int t = tid; t < T_; t += 64){
    float m = -3.0e38f;
    for (int c = 0; c < NTAG; c++) m = fmaxf(m, trell[t][c]);
    float s = 0.f;
    for (int c = 0; c < NTAG; c++) s += expf(trell[t][c] - m);
    float p = expf(trell[t][path[t]] - m) / s;
    out[64 + (size_t)b * T_ + t] = (float)path[t];          // path.T
    out[64 + 64 * T_ + (size_t)b * T_ + t] = p;             // probs.T
  }
}

extern "C" void kernel_launch(void* const* d_in, const int* in_sizes, int n_in,
                              void* d_out, int out_size, void* d_ws, size_t ws_size,
                              hipStream_t stream){
  (void)in_sizes; (void)n_in; (void)out_size; (void)ws_size;
  const int*   sents = (const int*)d_in[0];
  const float* emb   = (const float*)d_in[1];
  const float* wihF  = (const float*)d_in[2];
  const float* whhF  = (const float*)d_in[3];
  const float* bihF  = (const float*)d_in[4];
  const float* bhhF  = (const float*)d_in[5];
  const float* wihB  = (const float*)d_in[6];
  const float* whhB  = (const float*)d_in[7];
  const float* bihB  = (const float*)d_in[8];
  const float* bhhB  = (const float*)d_in[9];
  const float* wl    = (const float*)d_in[10];
  const float* bl    = (const float*)d_in[11];
  const float* trans = (const float*)d_in[12];
  const float* h0    = (const float*)d_in[13];
  const float* c0    = (const float*)d_in[14];

  float* wsf    = (float*)d_ws;
  ushort* q     = (ushort*)(wsf + Q_OFFF);
  float* gx     = wsf + GX_OFF;
  float* logits = wsf + LG_OFF;
  uint* flags   = (uint*)(wsf + FLG_OFF);
  float* out    = (float*)d_out;
  ushort* hsHi  = q + HS_HI;
  ushort* hsLo  = q + HS_LO;

  k0_split<<<1024, 256, 0, stream>>>(whhF, whhB, wihF, wihB, wl, h0, q, flags);
  k1_gx<<<dim3(16, 256, 2), 256, 0, stream>>>(sents, emb, q, bihF, bhhF, bihB, bhhB, gx);

  {
    const ushort* qa = q; const float* gxa = gx; const float* c0a = c0;
    ushort* hia = hsHi; ushort* loa = hsLo; uint* fla = flags;
    void* args[] = { (void*)&qa, (void*)&gxa, (void*)&c0a,
                     (void*)&hia, (void*)&loa, (void*)&fla };
    hipLaunchCooperativeKernel((const void*)k2_persist, dim3(256), dim3(256),
                               args, 0, stream);
  }

  k3_logits<<<256, 256, 0, stream>>>(q, bl, logits);
  k4_viterbi<<<64, 64, 0, stream>>>(logits, trans, out);
}